// Round 14
// baseline (204.386 us; speedup 1.0000x reference)
//
#include <hip/hip_runtime.h>
#include <math.h>

#define NN   32768
#define EE   524288
#define ETOT (EE + NN)
#define BB   32
#define NPG  1024
#define EPG  16384          // edges per graph (contiguous block in ei)
#define RPG  17408          // CSR entries per graph = 16384 + 1024 self-loops
#define KK   512
#define INC  128
#define HID  64
#define NH   4
#define CC   256
#define SLOPE 0.2f

typedef __attribute__((ext_vector_type(8))) short short8;   // 8 bf16 = 4 VGPRs
typedef __attribute__((ext_vector_type(4))) float f32x4;

static __device__ inline unsigned short f2bf(float f) {      // fp32 -> bf16 RNE
  unsigned u = __float_as_uint(f);
  unsigned r = (u + 0x7FFFu + ((u >> 16) & 1u)) >> 16;
  return (unsigned short)r;
}

// sign-aware float atomic max (exact; handles -0.0 via sign-bit test)
static __device__ inline void atomicMaxF(float* addr, float value) {
  if (!(__float_as_uint(value) >> 31)) {
    atomicMax((int*)addr, __float_as_int(value));
  } else {
    atomicMin((unsigned int*)addr, __float_as_uint(value));
  }
}

// ---------------- prep (1024 thr): consts+Mg (0-16) | transposes (17-64) | scan (65-96) ----------------
__global__ __launch_bounds__(1024) void prep_kernel(const float* __restrict__ W,
                                                    const float* __restrict__ a_src,
                                                    const float* __restrict__ a_dst,
                                                    const float* __restrict__ b_gat,
                                                    const float* __restrict__ W_lin,
                                                    const float* __restrict__ b_lin,
                                                    const float* __restrict__ p,
                                                    float* __restrict__ Mg,
                                                    float* __restrict__ cbuf,
                                                    unsigned short* __restrict__ Wt,
                                                    unsigned short* __restrict__ Wlt,
                                                    const int* __restrict__ ei,
                                                    int* __restrict__ row_ptr,
                                                    int* __restrict__ col) {
  const int b = blockIdx.x, t = threadIdx.x;
  if (b >= 65) {                                    // ---- scan_scatter (1024-thr) ----
    __shared__ int hist[NPG];
    __shared__ int lpos[NPG];
    __shared__ int wsum[16];
    const int bb = b - 65;
    const int lane = t & 63, wid = t >> 6;
    hist[t] = 0;
    __syncthreads();
    const int e0 = bb * EPG;
    for (int k = t; k < EPG; k += 1024)
      atomicAdd(&hist[ei[EE + e0 + k] - bb * NPG], 1);
    __syncthreads();
    const int c = hist[t] + 1;                      // + self-loop
    int inc = c;                                    // wave-level inclusive scan
#pragma unroll
    for (int off = 1; off < 64; off <<= 1) {
      int u = __shfl_up(inc, off, 64);
      if (lane >= off) inc += u;
    }
    if (lane == 63) wsum[wid] = inc;
    __syncthreads();
    if (wid == 0) {                                 // scan 16 wave totals
      int v = (lane < 16) ? wsum[lane] : 0;
#pragma unroll
      for (int off = 1; off < 16; off <<= 1) {
        int u = __shfl_up(v, off, 64);
        if (lane >= off) v += u;
      }
      if (lane < 16) wsum[lane] = v;                // inclusive
    }
    __syncthreads();
    const int woff = (wid == 0) ? 0 : wsum[wid - 1];
    const int excl = woff + inc - c;                // block-local exclusive prefix
    row_ptr[bb * NPG + t] = bb * RPG + excl;
    lpos[t] = excl;
    if (bb == 0 && t == 0) row_ptr[NN] = ETOT;
    __syncthreads();
    {                                               // self-loop entry for node t
      int p0 = atomicAdd(&lpos[t], 1);
      col[bb * RPG + p0] = bb * NPG + t;
    }
    for (int k = t; k < EPG; k += 1024) {
      int s = ei[e0 + k];
      int d = ei[EE + e0 + k];
      int p1 = atomicAdd(&lpos[d - bb * NPG], 1);
      col[bb * RPG + p1] = s;
    }
    return;
  }
  if (b >= 17) {                                    // ---- transposes (1024 thr) ----
    int idx = (b - 17) * 1024 + t;
    if (idx < 32768) {                              // Wt[c][k] = W[k][c]
      int c = idx >> 7, k = idx & 127;
      Wt[idx] = f2bf(W[k * 256 + c]);
    } else {                                        // Wlt[c][k] = W_lin[k][c]
      int i2 = idx - 32768;
      int c = i2 >> 8, k = i2 & 255;
      Wlt[i2] = f2bf(W_lin[k * 64 + c]);
    }
    return;
  }
  // ---- blocks 0..16: consts + Mg (original 256-thr arithmetic, t<256 guards) ----
  __shared__ float pl[64];
  __shared__ float ql[256];
  __shared__ float red[256];
  __shared__ float red2[256];
  if (t < 64) pl[t] = p[t];
  __syncthreads();
  if (t < 256) {                                    // ql[t] = dot(W_lin[t], p)
    float acc = 0.f;
    const float* wr = W_lin + t * 64;
#pragma unroll
    for (int c = 0; c < 64; c += 4) {
      float4 wv = *(const float4*)(wr + c);
      acc += wv.x * pl[c] + wv.y * pl[c + 1] + wv.z * pl[c + 2] + wv.w * pl[c + 3];
    }
    ql[t] = acc;
  }
  __syncthreads();
  if (b == 0) {                                     // cq + rnorm via LDS trees
    if (t < 256) {
      float r = ql[t] * b_gat[t];
      if (t < 64) r += b_lin[t] * pl[t];
      red[t] = r;
      red2[t] = (t < 64) ? pl[t] * pl[t] : 0.f;
    }
    __syncthreads();
    for (int s2 = 128; s2 > 0; s2 >>= 1) {
      if (t < s2) { red[t] += red[t + s2]; red2[t] += red2[t + s2]; }
      __syncthreads();
    }
    if (t == 0) { cbuf[0] = red[0]; cbuf[1] = 1.0f / sqrtf(red2[0]); }
    return;
  }
  if (t < 96) {                                     // blocks 1..16: 8 rows x 12 cols
    const int i = (b - 1) * 8 + t / 12;
    const int j = t % 12;
    const int hh = j & 3;
    const float* wr = W + i * 256 + hh * 64;
    float acc = 0.f;
    if (j < 8) {
      const float* v = (j < 4 ? a_src : a_dst) + hh * 64;
#pragma unroll
      for (int c = 0; c < 64; c += 4) {
        float4 wv = *(const float4*)(wr + c);
        float4 vv = *(const float4*)(v + c);
        acc += wv.x * vv.x + wv.y * vv.y + wv.z * vv.z + wv.w * vv.w;
      }
    } else {
#pragma unroll
      for (int c = 0; c < 64; ++c) acc += wr[c] * ql[hh * 64 + c];
    }
    Mg[i * 12 + j] = acc;
  }
}

// ---------------- stage2: gemm1 (0-511) + prep_node split-staged (512-1023) ----------------
// R14: prep_node stages x in TWO channel-halves through xs[64][68] -> LDS drops
// 40.1KB -> 23.7KB -> 6 blocks/CU (24 waves) instead of 3 (12). The dot still
// accumulates c4=0..31 ascending with identical float4 expressions -> al_s/al_d/hq
// bit-identical to R11 (score path untouched). Staging stays wave-coalesced
// (16 lanes x 16B per 256B half-row). gemm1 half unchanged.
__global__ __launch_bounds__(256) void stage2_kernel(const float* __restrict__ x,
                                                     const float* __restrict__ Mg,
                                                     const unsigned short* __restrict__ Wt,
                                                     float* __restrict__ al_s,
                                                     float* __restrict__ al_d,
                                                     float* __restrict__ hq,
                                                     unsigned short* __restrict__ hbf) {
  __shared__ float smem[64 * 68 + 12 * 132];        // xs[64][68] + MsT[12][132] = 23.7KB
  const int t = threadIdx.x;
  if (blockIdx.x >= 512) {
    // ---- prep_node half (split-staged) ----
    float (*xs)[68] = (float(*)[68])smem;
    float (*MsT)[132] = (float(*)[132])(smem + 64 * 68);
    const int n0 = (blockIdx.x - 512) * 64;
    for (int r = t; r < 1536; r += 256) MsT[r % 12][r / 12] = Mg[r];
    const int node = t >> 2, q = t & 3;
    const int j0 = q * 3;
    float a0 = 0.f, a1 = 0.f, a2 = 0.f;
    // half 0: channels 0..63 (c4 0..15)
#pragma unroll
    for (int u = 0; u < 4; ++u) {
      int idx = u * 256 + t;                        // node*16 + c4h
      int nd = idx >> 4, c4 = idx & 15;
      *(float4*)(&xs[nd][c4 * 4]) =
          *(const float4*)(x + (size_t)(n0 + nd) * 128 + c4 * 4);
    }
    __syncthreads();
#pragma unroll
    for (int c4 = 0; c4 < 16; ++c4) {
      float4 xv = *(const float4*)(&xs[node][c4 * 4]);
      float4 m0 = *(const float4*)(&MsT[j0 + 0][c4 * 4]);
      float4 m1 = *(const float4*)(&MsT[j0 + 1][c4 * 4]);
      float4 m2 = *(const float4*)(&MsT[j0 + 2][c4 * 4]);
      a0 += xv.x * m0.x + xv.y * m0.y + xv.z * m0.z + xv.w * m0.w;
      a1 += xv.x * m1.x + xv.y * m1.y + xv.z * m1.z + xv.w * m1.w;
      a2 += xv.x * m2.x + xv.y * m2.y + xv.z * m2.z + xv.w * m2.w;
    }
    __syncthreads();                                // xs about to be overwritten
    // half 1: channels 64..127 (c4 16..31)
#pragma unroll
    for (int u = 0; u < 4; ++u) {
      int idx = u * 256 + t;
      int nd = idx >> 4, c4 = idx & 15;
      *(float4*)(&xs[nd][c4 * 4]) =
          *(const float4*)(x + (size_t)(n0 + nd) * 128 + 64 + c4 * 4);
    }
    __syncthreads();
#pragma unroll
    for (int c4 = 0; c4 < 16; ++c4) {
      float4 xv = *(const float4*)(&xs[node][c4 * 4]);
      float4 m0 = *(const float4*)(&MsT[j0 + 0][(16 + c4) * 4]);
      float4 m1 = *(const float4*)(&MsT[j0 + 1][(16 + c4) * 4]);
      float4 m2 = *(const float4*)(&MsT[j0 + 2][(16 + c4) * 4]);
      a0 += xv.x * m0.x + xv.y * m0.y + xv.z * m0.z + xv.w * m0.w;
      a1 += xv.x * m1.x + xv.y * m1.y + xv.z * m1.z + xv.w * m1.w;
      a2 += xv.x * m2.x + xv.y * m2.y + xv.z * m2.z + xv.w * m2.w;
    }
    const int n = n0 + node;
    float vals[3] = {a0, a1, a2};
#pragma unroll
    for (int k = 0; k < 3; ++k) {
      int j = j0 + k;
      float* base = (j < 4) ? al_s : ((j < 8) ? al_d : hq);
      int jj = (j < 4) ? j : ((j < 8) ? j - 4 : j - 8);
      base[n * 4 + jj] = vals[k];
    }
    return;
  }
  // ---- gemm1 half (unchanged) ----
  const int lane = t & 63;
  const int wv = t >> 6;
  const int q = lane >> 4, nh = lane & 15;
  const int lid = blockIdx.x;                       // 512 blocks = 8 xcd x 64
  const int node = ((lid & 7) * 64 + (lid >> 3)) * 64 + wv * 16 + nh;
  f32x4 acc[16];
#pragma unroll
  for (int mt = 0; mt < 16; ++mt) acc[mt] = (f32x4){0.f, 0.f, 0.f, 0.f};
  const float* xr = x + (size_t)node * 128;
#pragma unroll
  for (int kc = 0; kc < 4; ++kc) {
    const float* xp = xr + kc * 32 + q * 8;
    float4 v0 = *(const float4*)(xp);
    float4 v1 = *(const float4*)(xp + 4);
    short8 b;
    b[0] = (short)f2bf(v0.x); b[1] = (short)f2bf(v0.y);
    b[2] = (short)f2bf(v0.z); b[3] = (short)f2bf(v0.w);
    b[4] = (short)f2bf(v1.x); b[5] = (short)f2bf(v1.y);
    b[6] = (short)f2bf(v1.z); b[7] = (short)f2bf(v1.w);
#pragma unroll
    for (int mt = 0; mt < 16; ++mt) {
      short8 a = *(const short8*)(Wt + (size_t)(mt * 16 + nh) * 128 + kc * 32 + q * 8);
      acc[mt] = __builtin_amdgcn_mfma_f32_16x16x32_bf16(a, b, acc[mt], 0, 0, 0);
    }
  }
  unsigned short* hr = hbf + (size_t)node * 256;
#pragma unroll
  for (int mt = 0; mt < 16; ++mt) {
    ushort4 o;
    o.x = f2bf(acc[mt][0]); o.y = f2bf(acc[mt][1]);
    o.z = f2bf(acc[mt][2]); o.w = f2bf(acc[mt][3]);
    *(ushort4*)(hr + mt * 16 + q * 4) = o;
  }
}

// ---------------- aggregation: 4-deep clamped prefetch ----------------
__global__ __launch_bounds__(256) void agg_kernel(const unsigned short* __restrict__ h,
                                                  const float* __restrict__ al_s,
                                                  const float* __restrict__ al_d,
                                                  const float* __restrict__ hq,
                                                  const int* __restrict__ row_ptr,
                                                  const int* __restrict__ col,
                                                  const float* __restrict__ b_gat,
                                                  const float* __restrict__ cbuf,
                                                  unsigned short* __restrict__ outg,
                                                  float* __restrict__ score) {
  __shared__ float wsh[4][256];
  __shared__ float qsh[4][256];
  __shared__ int   osh[4][64];
  const int lane = threadIdx.x & 63;
  const int wv = threadIdx.x >> 6;
  const int hqi = lane >> 4;                        // head of this lane
  const int xcd = blockIdx.x & 7;
  const int jb = blockIdx.x >> 3;
  const int n = (xcd * 1024 + jb) * 4 + wv;
  const int beg = row_ptr[n], end = row_ptr[n + 1];
  const float4 ad4 = *(const float4*)(al_d + (size_t)n * 4);   // wave-uniform
  const char* hbase = (const char*)h + (size_t)lane * 8;
  float ax = 0.f, ay = 0.f, az = 0.f, aw = 0.f, den = 0.f, sq = 0.f;
  for (int base = beg; base < end; base += 64) {
    const int rem = end - base;
    const int cnt = rem < 64 ? rem : 64;
    if (lane < cnt) {
      const int c = col[base + lane];
      osh[wv][lane] = c << 9;                        // byte offset (256 ch x 2B)
      const float4 as = *(const float4*)(al_s + (size_t)c * 4);
      float e0 = as.x + ad4.x; e0 = (e0 > 0.f) ? e0 : SLOPE * e0;
      float e1 = as.y + ad4.y; e1 = (e1 > 0.f) ? e1 : SLOPE * e1;
      float e2 = as.z + ad4.z; e2 = (e2 > 0.f) ? e2 : SLOPE * e2;
      float e3 = as.w + ad4.w; e3 = (e3 > 0.f) ? e3 : SLOPE * e3;
      *(float4*)(&wsh[wv][lane * 4]) =
          make_float4(__expf(e0), __expf(e1), __expf(e2), __expf(e3));
      *(float4*)(&qsh[wv][lane * 4]) = *(const float4*)(hq + (size_t)c * 4);
    }
    // wave-coherent LDS region (per-wave, no barrier needed)
    const int cm1 = cnt - 1;
    uint2 v0 = *(const uint2*)(hbase + osh[wv][0]);
    uint2 v1 = *(const uint2*)(hbase + osh[wv][1 > cm1 ? cm1 : 1]);
    uint2 v2 = *(const uint2*)(hbase + osh[wv][2 > cm1 ? cm1 : 2]);
    uint2 v3 = *(const uint2*)(hbase + osh[wv][3 > cm1 ? cm1 : 3]);
    for (int i = 0; i < cnt; ++i) {
      const float w = wsh[wv][i * 4 + hqi];
      const float hqv = qsh[wv][i * 4 + hqi];
      uint2 cur = v0; v0 = v1; v1 = v2; v2 = v3;
      int ni = i + 4; ni = ni > cm1 ? cm1 : ni;
      v3 = *(const uint2*)(hbase + osh[wv][ni]);
      den += w; sq += w * hqv;
      ax += w * __uint_as_float(cur.x << 16);
      ay += w * __uint_as_float(cur.x & 0xffff0000u);
      az += w * __uint_as_float(cur.y << 16);
      aw += w * __uint_as_float(cur.y & 0xffff0000u);
    }
  }
  const float4 bg = *(const float4*)(b_gat + lane * 4);
  ushort4 ov;
  ov.x = f2bf(ax / den + bg.x); ov.y = f2bf(ay / den + bg.y);
  ov.z = f2bf(az / den + bg.z); ov.w = f2bf(aw / den + bg.w);
  *(ushort4*)(outg + (size_t)n * 256 + lane * 4) = ov;
  float sd = sq / den;                              // per-head (uniform within head)
  float s0v = __shfl(sd, 0), s1v = __shfl(sd, 16);
  float s2v = __shfl(sd, 32), s3v = __shfl(sd, 48);
  if (lane == 0)
    score[n] = tanhf((s0v + s1v + s2v + s3v + cbuf[0]) * cbuf[1]);
}

// ---------------- top-k rank selection, 8 slices/graph (256 blocks) + x1 init ----------------
__global__ __launch_bounds__(1024) void topk_kernel(const float* __restrict__ score,
                                                    int* __restrict__ pidx_g,
                                                    float* __restrict__ tvs_g,
                                                    int* __restrict__ nmap,
                                                    float* __restrict__ out_batch,
                                                    float* __restrict__ out_x1) {
  __shared__ float scv[NPG];
  const int blk = blockIdx.x;                       // 256 = 32 graphs x 8 slices
  const int b = blk >> 3, slice = blk & 7;
  const int t = threadIdx.x;
  if (slice == 0 && t < 128)                        // init x1 for final's atomics
    out_x1[b * 128 + t] = (t < 64) ? 0.f : -INFINITY;
  scv[t] = score[b * NPG + t];
  __syncthreads();
  const int node = slice * 128 + (t >> 3);          // node within graph
  const int sub = t & 7;
  const float sc = scv[node];
  int rank = 0;
#pragma unroll
  for (int m = 0; m < 32; ++m) {
    const int j = (m * 8 + sub) * 4;
    const float4 s4 = *(const float4*)(&scv[j]);
    rank += (s4.x > sc) || (s4.x == sc && (j + 0) < node);
    rank += (s4.y > sc) || (s4.y == sc && (j + 1) < node);
    rank += (s4.z > sc) || (s4.z == sc && (j + 2) < node);
    rank += (s4.w > sc) || (s4.w == sc && (j + 3) < node);
  }
  rank += __shfl_xor(rank, 1, 64);                  // sum over sub (lane bits 0-2)
  rank += __shfl_xor(rank, 2, 64);
  rank += __shfl_xor(rank, 4, 64);
  if (sub == 0) {
    const int gn = b * NPG + node;
    if (rank < KK) {
      pidx_g[b * KK + rank] = node;
      tvs_g[b * KK + rank] = sc;
      nmap[gn] = b * KK + rank;
      out_batch[b * KK + rank] = (float)b;
    } else {
      nmap[gn] = -1;
    }
  }
}

// ---------------- final: gemm2xp + pool-atomics (blocks 0-255) | edge remap (256-2303) ----------------
__global__ __launch_bounds__(256) void final_kernel(const unsigned short* __restrict__ outg,
                                                    const unsigned short* __restrict__ Wlt,
                                                    const float* __restrict__ bl,
                                                    const int* __restrict__ pidx_g,
                                                    const float* __restrict__ tvs_g,
                                                    const int* __restrict__ ei,
                                                    const float* __restrict__ edge,
                                                    const int* __restrict__ nmap,
                                                    float* __restrict__ out_xp,
                                                    float* __restrict__ out_ei,
                                                    float* __restrict__ out_edge,
                                                    float* __restrict__ out_x1) {
  __shared__ float tile[64][68];
  __shared__ float pr[4][64];
  __shared__ float pmx[4][64];
  const int t = threadIdx.x;
  if (blockIdx.x >= 256) {                          // ---- edge remap / filter ----
    int e = (blockIdx.x - 256) * 256 + t;
    int s = ei[e], d = ei[EE + e];
    int ns = nmap[s], nd = nmap[d];
    bool valid = (ns >= 0) && (nd >= 0);
    out_ei[e] = (float)(valid ? ns : -1);
    out_ei[EE + e] = (float)(valid ? nd : -1);
    const float4* ef = (const float4*)(edge + (size_t)e * 8);
    float4 z = make_float4(0.f, 0.f, 0.f, 0.f);
    float4 v0 = valid ? ef[0] : z;
    float4 v1 = valid ? ef[1] : z;
    float4* eo = (float4*)(out_edge + (size_t)e * 8);
    eo[0] = v0; eo[1] = v1;
    return;
  }
  // ---- gemm2xp + pool partials ----
  const int lane = t & 63, wv = t >> 6;
  const int q = lane >> 4, nh = lane & 15;
  const int g = blockIdx.x >> 3, o = blockIdx.x & 7;
  const int r = o * 64 + wv * 16 + nh;              // kept-row rank within graph
  const int row = wv * 16 + nh;
  const int gnode = g * NPG + pidx_g[g * KK + r];
  const float tv = tvs_g[g * KK + r];
  f32x4 acc[4];
#pragma unroll
  for (int mt = 0; mt < 4; ++mt) acc[mt] = (f32x4){0.f, 0.f, 0.f, 0.f};
  const unsigned short* ar = outg + (size_t)gnode * 256;
#pragma unroll
  for (int kc = 0; kc < 8; ++kc) {
    short8 bf = *(const short8*)(ar + kc * 32 + q * 8);
#pragma unroll
    for (int mt = 0; mt < 4; ++mt) {
      short8 a = *(const short8*)(Wlt + (size_t)(mt * 16 + nh) * 256 + kc * 32 + q * 8);
      acc[mt] = __builtin_amdgcn_mfma_f32_16x16x32_bf16(a, bf, acc[mt], 0, 0, 0);
    }
  }
#pragma unroll
  for (int mt = 0; mt < 4; ++mt) {
    const int c4 = mt * 16 + q * 4;
    float4 bl4 = *(const float4*)(bl + c4);
    float4 o4 = make_float4((acc[mt][0] + bl4.x) * tv, (acc[mt][1] + bl4.y) * tv,
                            (acc[mt][2] + bl4.z) * tv, (acc[mt][3] + bl4.w) * tv);
    *(float4*)(out_xp + (size_t)(g * KK + r) * HID + c4) = o4;
    *(float4*)(&tile[row][c4]) = o4;
  }
  __syncthreads();
  {                                                 // partial sum/max over 64 rows
    const int ch = t & 63, qr = t >> 6;
    float s = 0.f, m = -INFINITY;
#pragma unroll
    for (int rr = 0; rr < 16; ++rr) {
      float v = tile[qr * 16 + rr][ch];
      s += v; m = fmaxf(m, v);
    }
    pr[qr][ch] = s; pmx[qr][ch] = m;
  }
  __syncthreads();
  if (t < 64) {
    float s = pr[0][t] + pr[1][t] + pr[2][t] + pr[3][t];
    float m = fmaxf(fmaxf(pmx[0][t], pmx[1][t]), fmaxf(pmx[2][t], pmx[3][t]));
    atomicAdd(&out_x1[g * 128 + t], s * (1.0f / KK));
    atomicMaxF(&out_x1[g * 128 + 64 + t], m);
  }
}

extern "C" void kernel_launch(void* const* d_in, const int* in_sizes, int n_in,
                              void* d_out, int out_size, void* d_ws, size_t ws_size,
                              hipStream_t stream) {
  const float* x      = (const float*)d_in[0];
  const int*   ei     = (const int*)d_in[1];
  const float* edge   = (const float*)d_in[2];
  const float* W      = (const float*)d_in[4];
  const float* a_src  = (const float*)d_in[5];
  const float* a_dst  = (const float*)d_in[6];
  const float* b_gat  = (const float*)d_in[7];
  const float* W_lin  = (const float*)d_in[8];
  const float* b_lin  = (const float*)d_in[9];
  const float* p_pool = (const float*)d_in[10];

  char* ws = (char*)d_ws;
  size_t off = 0;
  auto alloc = [&](size_t bytes) -> void* {
    void* p = ws + off;
    off += (bytes + 255) & ~(size_t)255;
    return p;
  };
  unsigned short* hbf  = (unsigned short*)alloc((size_t)NN * CC * 2);
  unsigned short* outg = (unsigned short*)alloc((size_t)NN * CC * 2);
  float* al_s    = (float*)alloc((size_t)NN * NH * 4);
  float* al_d    = (float*)alloc((size_t)NN * NH * 4);
  float* hq      = (float*)alloc((size_t)NN * NH * 4);
  float* score   = (float*)alloc((size_t)NN * 4);
  int*   row_ptr = (int*)alloc((size_t)(NN + 1) * 4);
  int*   col     = (int*)alloc((size_t)ETOT * 4);
  int*   nmap    = (int*)alloc((size_t)NN * 4);
  int*   pidx_g  = (int*)alloc((size_t)BB * KK * 4);
  float* tvs_g   = (float*)alloc((size_t)BB * KK * 4);
  unsigned short* Wt  = (unsigned short*)alloc((size_t)CC * INC * 2);
  unsigned short* Wlt = (unsigned short*)alloc((size_t)HID * CC * 2);
  float* Mg      = (float*)alloc((size_t)INC * 12 * 4);
  float* cbuf    = (float*)alloc(2 * 4);

  float* out_xp    = (float*)d_out;
  float* out_ei    = out_xp + (size_t)BB * KK * HID;
  float* out_edge  = out_ei + 2 * (size_t)EE;
  float* out_batch = out_edge + (size_t)EE * 8;
  float* out_x1    = out_batch + (size_t)BB * KK;

  prep_kernel<<<97, 1024, 0, stream>>>(W, a_src, a_dst, b_gat, W_lin, b_lin,
                                       p_pool, Mg, cbuf, Wt, Wlt, ei, row_ptr, col);
  stage2_kernel<<<1024, 256, 0, stream>>>(x, Mg, Wt, al_s, al_d, hq, hbf);
  agg_kernel<<<NN / 4, 256, 0, stream>>>(hbf, al_s, al_d, hq, row_ptr, col,
                                         b_gat, cbuf, outg, score);
  topk_kernel<<<256, 1024, 0, stream>>>(score, pidx_g, tvs_g, nmap, out_batch,
                                        out_x1);
  final_kernel<<<2304, 256, 0, stream>>>(outg, Wlt, b_lin, pidx_g, tvs_g,
                                         ei, edge, nmap, out_xp, out_ei,
                                         out_edge, out_x1);
}

// Round 15
// 198.902 us; speedup vs baseline: 1.0276x; 1.0276x over previous
//
#include <hip/hip_runtime.h>
#include <math.h>

#define NN   32768
#define EE   524288
#define ETOT (EE + NN)
#define BB   32
#define NPG  1024
#define EPG  16384          // edges per graph (contiguous block in ei)
#define RPG  17408          // CSR entries per graph = 16384 + 1024 self-loops
#define KK   512
#define INC  128
#define HID  64
#define NH   4
#define CC   256
#define SLOPE 0.2f

typedef __attribute__((ext_vector_type(8))) short short8;   // 8 bf16 = 4 VGPRs
typedef __attribute__((ext_vector_type(4))) float f32x4;

static __device__ inline unsigned short f2bf(float f) {      // fp32 -> bf16 RNE
  unsigned u = __float_as_uint(f);
  unsigned r = (u + 0x7FFFu + ((u >> 16) & 1u)) >> 16;
  return (unsigned short)r;
}

// sign-aware float atomic max (exact; handles -0.0 via sign-bit test)
static __device__ inline void atomicMaxF(float* addr, float value) {
  if (!(__float_as_uint(value) >> 31)) {
    atomicMax((int*)addr, __float_as_int(value));
  } else {
    atomicMin((unsigned int*)addr, __float_as_uint(value));
  }
}

// ---------------- prep (1024 thr): consts+Mg (0-16) | transposes (17-64) | scan (65-96) ----------------
// Session ledger: R10 scan-in-stage2 (256thr tail) +0; R12 micro-rewrites +10.6;
// R14 occupancy split +3 -> this R11 form is the measured best (199.7us).
__global__ __launch_bounds__(1024) void prep_kernel(const float* __restrict__ W,
                                                    const float* __restrict__ a_src,
                                                    const float* __restrict__ a_dst,
                                                    const float* __restrict__ b_gat,
                                                    const float* __restrict__ W_lin,
                                                    const float* __restrict__ b_lin,
                                                    const float* __restrict__ p,
                                                    float* __restrict__ Mg,
                                                    float* __restrict__ cbuf,
                                                    unsigned short* __restrict__ Wt,
                                                    unsigned short* __restrict__ Wlt,
                                                    const int* __restrict__ ei,
                                                    int* __restrict__ row_ptr,
                                                    int* __restrict__ col) {
  const int b = blockIdx.x, t = threadIdx.x;
  if (b >= 65) {                                    // ---- scan_scatter (1024-thr) ----
    __shared__ int hist[NPG];
    __shared__ int lpos[NPG];
    __shared__ int wsum[16];
    const int bb = b - 65;
    const int lane = t & 63, wid = t >> 6;
    hist[t] = 0;
    __syncthreads();
    const int e0 = bb * EPG;
    for (int k = t; k < EPG; k += 1024)
      atomicAdd(&hist[ei[EE + e0 + k] - bb * NPG], 1);
    __syncthreads();
    const int c = hist[t] + 1;                      // + self-loop
    int inc = c;                                    // wave-level inclusive scan
#pragma unroll
    for (int off = 1; off < 64; off <<= 1) {
      int u = __shfl_up(inc, off, 64);
      if (lane >= off) inc += u;
    }
    if (lane == 63) wsum[wid] = inc;
    __syncthreads();
    if (wid == 0) {                                 // scan 16 wave totals
      int v = (lane < 16) ? wsum[lane] : 0;
#pragma unroll
      for (int off = 1; off < 16; off <<= 1) {
        int u = __shfl_up(v, off, 64);
        if (lane >= off) v += u;
      }
      if (lane < 16) wsum[lane] = v;                // inclusive
    }
    __syncthreads();
    const int woff = (wid == 0) ? 0 : wsum[wid - 1];
    const int excl = woff + inc - c;                // block-local exclusive prefix
    row_ptr[bb * NPG + t] = bb * RPG + excl;
    lpos[t] = excl;
    if (bb == 0 && t == 0) row_ptr[NN] = ETOT;
    __syncthreads();
    {                                               // self-loop entry for node t
      int p0 = atomicAdd(&lpos[t], 1);
      col[bb * RPG + p0] = bb * NPG + t;
    }
    for (int k = t; k < EPG; k += 1024) {
      int s = ei[e0 + k];
      int d = ei[EE + e0 + k];
      int p1 = atomicAdd(&lpos[d - bb * NPG], 1);
      col[bb * RPG + p1] = s;
    }
    return;
  }
  if (b >= 17) {                                    // ---- transposes (1024 thr) ----
    int idx = (b - 17) * 1024 + t;
    if (idx < 32768) {                              // Wt[c][k] = W[k][c]
      int c = idx >> 7, k = idx & 127;
      Wt[idx] = f2bf(W[k * 256 + c]);
    } else {                                        // Wlt[c][k] = W_lin[k][c]
      int i2 = idx - 32768;
      int c = i2 >> 8, k = i2 & 255;
      Wlt[i2] = f2bf(W_lin[k * 64 + c]);
    }
    return;
  }
  // ---- blocks 0..16: consts + Mg (original 256-thr arithmetic, t<256 guards) ----
  __shared__ float pl[64];
  __shared__ float ql[256];
  __shared__ float red[256];
  __shared__ float red2[256];
  if (t < 64) pl[t] = p[t];
  __syncthreads();
  if (t < 256) {                                    // ql[t] = dot(W_lin[t], p)
    float acc = 0.f;
    const float* wr = W_lin + t * 64;
#pragma unroll
    for (int c = 0; c < 64; c += 4) {
      float4 wv = *(const float4*)(wr + c);
      acc += wv.x * pl[c] + wv.y * pl[c + 1] + wv.z * pl[c + 2] + wv.w * pl[c + 3];
    }
    ql[t] = acc;
  }
  __syncthreads();
  if (b == 0) {                                     // cq + rnorm via LDS trees
    if (t < 256) {
      float r = ql[t] * b_gat[t];
      if (t < 64) r += b_lin[t] * pl[t];
      red[t] = r;
      red2[t] = (t < 64) ? pl[t] * pl[t] : 0.f;
    }
    __syncthreads();
    for (int s2 = 128; s2 > 0; s2 >>= 1) {
      if (t < s2) { red[t] += red[t + s2]; red2[t] += red2[t + s2]; }
      __syncthreads();
    }
    if (t == 0) { cbuf[0] = red[0]; cbuf[1] = 1.0f / sqrtf(red2[0]); }
    return;
  }
  if (t < 96) {                                     // blocks 1..16: 8 rows x 12 cols
    const int i = (b - 1) * 8 + t / 12;
    const int j = t % 12;
    const int hh = j & 3;
    const float* wr = W + i * 256 + hh * 64;
    float acc = 0.f;
    if (j < 8) {
      const float* v = (j < 4 ? a_src : a_dst) + hh * 64;
#pragma unroll
      for (int c = 0; c < 64; c += 4) {
        float4 wv = *(const float4*)(wr + c);
        float4 vv = *(const float4*)(v + c);
        acc += wv.x * vv.x + wv.y * vv.y + wv.z * vv.z + wv.w * vv.w;
      }
    } else {
#pragma unroll
      for (int c = 0; c < 64; ++c) acc += wr[c] * ql[hh * 64 + c];
    }
    Mg[i * 12 + j] = acc;
  }
}

// ---------------- stage2 (R9/R11 form): gemm1 (0-511) + prep_node (512-1023) ----------------
__global__ __launch_bounds__(256) void stage2_kernel(const float* __restrict__ x,
                                                     const float* __restrict__ Mg,
                                                     const unsigned short* __restrict__ Wt,
                                                     float* __restrict__ al_s,
                                                     float* __restrict__ al_d,
                                                     float* __restrict__ hq,
                                                     unsigned short* __restrict__ hbf) {
  __shared__ float smem[76 * 132];                  // xs[64][132] + MsT[12][132]
  const int t = threadIdx.x;
  if (blockIdx.x >= 512) {
    // ---- prep_node half ----
    float (*xs)[132] = (float(*)[132])smem;
    float (*MsT)[132] = (float(*)[132])(smem + 64 * 132);
    const int n0 = (blockIdx.x - 512) * 64;
    for (int r = t; r < 1536; r += 256) MsT[r % 12][r / 12] = Mg[r];
#pragma unroll
    for (int u = 0; u < 8; ++u) {
      int idx = u * 256 + t;                        // node*32 + c4
      int node = idx >> 5, c4 = idx & 31;
      *(float4*)(&xs[node][c4 * 4]) =
          *(const float4*)(x + (size_t)(n0 + node) * 128 + c4 * 4);
    }
    __syncthreads();
    const int node = t >> 2, q = t & 3;
    const int j0 = q * 3;
    float a0 = 0.f, a1 = 0.f, a2 = 0.f;
#pragma unroll
    for (int c4 = 0; c4 < 32; ++c4) {
      float4 xv = *(const float4*)(&xs[node][c4 * 4]);
      float4 m0 = *(const float4*)(&MsT[j0 + 0][c4 * 4]);
      float4 m1 = *(const float4*)(&MsT[j0 + 1][c4 * 4]);
      float4 m2 = *(const float4*)(&MsT[j0 + 2][c4 * 4]);
      a0 += xv.x * m0.x + xv.y * m0.y + xv.z * m0.z + xv.w * m0.w;
      a1 += xv.x * m1.x + xv.y * m1.y + xv.z * m1.z + xv.w * m1.w;
      a2 += xv.x * m2.x + xv.y * m2.y + xv.z * m2.z + xv.w * m2.w;
    }
    const int n = n0 + node;
    float vals[3] = {a0, a1, a2};
#pragma unroll
    for (int k = 0; k < 3; ++k) {
      int j = j0 + k;
      float* base = (j < 4) ? al_s : ((j < 8) ? al_d : hq);
      int jj = (j < 4) ? j : ((j < 8) ? j - 4 : j - 8);
      base[n * 4 + jj] = vals[k];
    }
    return;
  }
  // ---- gemm1 half ----
  const int lane = t & 63;
  const int wv = t >> 6;
  const int q = lane >> 4, nh = lane & 15;
  const int lid = blockIdx.x;                       // 512 blocks = 8 xcd x 64
  const int node = ((lid & 7) * 64 + (lid >> 3)) * 64 + wv * 16 + nh;
  f32x4 acc[16];
#pragma unroll
  for (int mt = 0; mt < 16; ++mt) acc[mt] = (f32x4){0.f, 0.f, 0.f, 0.f};
  const float* xr = x + (size_t)node * 128;
#pragma unroll
  for (int kc = 0; kc < 4; ++kc) {
    const float* xp = xr + kc * 32 + q * 8;
    float4 v0 = *(const float4*)(xp);
    float4 v1 = *(const float4*)(xp + 4);
    short8 b;
    b[0] = (short)f2bf(v0.x); b[1] = (short)f2bf(v0.y);
    b[2] = (short)f2bf(v0.z); b[3] = (short)f2bf(v0.w);
    b[4] = (short)f2bf(v1.x); b[5] = (short)f2bf(v1.y);
    b[6] = (short)f2bf(v1.z); b[7] = (short)f2bf(v1.w);
#pragma unroll
    for (int mt = 0; mt < 16; ++mt) {
      short8 a = *(const short8*)(Wt + (size_t)(mt * 16 + nh) * 128 + kc * 32 + q * 8);
      acc[mt] = __builtin_amdgcn_mfma_f32_16x16x32_bf16(a, b, acc[mt], 0, 0, 0);
    }
  }
  unsigned short* hr = hbf + (size_t)node * 256;
#pragma unroll
  for (int mt = 0; mt < 16; ++mt) {
    ushort4 o;
    o.x = f2bf(acc[mt][0]); o.y = f2bf(acc[mt][1]);
    o.z = f2bf(acc[mt][2]); o.w = f2bf(acc[mt][3]);
    *(ushort4*)(hr + mt * 16 + q * 4) = o;
  }
}

// ---------------- aggregation: 4-deep clamped prefetch ----------------
__global__ __launch_bounds__(256) void agg_kernel(const unsigned short* __restrict__ h,
                                                  const float* __restrict__ al_s,
                                                  const float* __restrict__ al_d,
                                                  const float* __restrict__ hq,
                                                  const int* __restrict__ row_ptr,
                                                  const int* __restrict__ col,
                                                  const float* __restrict__ b_gat,
                                                  const float* __restrict__ cbuf,
                                                  unsigned short* __restrict__ outg,
                                                  float* __restrict__ score) {
  __shared__ float wsh[4][256];
  __shared__ float qsh[4][256];
  __shared__ int   osh[4][64];
  const int lane = threadIdx.x & 63;
  const int wv = threadIdx.x >> 6;
  const int hqi = lane >> 4;                        // head of this lane
  const int xcd = blockIdx.x & 7;
  const int jb = blockIdx.x >> 3;
  const int n = (xcd * 1024 + jb) * 4 + wv;
  const int beg = row_ptr[n], end = row_ptr[n + 1];
  const float4 ad4 = *(const float4*)(al_d + (size_t)n * 4);   // wave-uniform
  const char* hbase = (const char*)h + (size_t)lane * 8;
  float ax = 0.f, ay = 0.f, az = 0.f, aw = 0.f, den = 0.f, sq = 0.f;
  for (int base = beg; base < end; base += 64) {
    const int rem = end - base;
    const int cnt = rem < 64 ? rem : 64;
    if (lane < cnt) {
      const int c = col[base + lane];
      osh[wv][lane] = c << 9;                        // byte offset (256 ch x 2B)
      const float4 as = *(const float4*)(al_s + (size_t)c * 4);
      float e0 = as.x + ad4.x; e0 = (e0 > 0.f) ? e0 : SLOPE * e0;
      float e1 = as.y + ad4.y; e1 = (e1 > 0.f) ? e1 : SLOPE * e1;
      float e2 = as.z + ad4.z; e2 = (e2 > 0.f) ? e2 : SLOPE * e2;
      float e3 = as.w + ad4.w; e3 = (e3 > 0.f) ? e3 : SLOPE * e3;
      *(float4*)(&wsh[wv][lane * 4]) =
          make_float4(__expf(e0), __expf(e1), __expf(e2), __expf(e3));
      *(float4*)(&qsh[wv][lane * 4]) = *(const float4*)(hq + (size_t)c * 4);
    }
    // wave-coherent LDS region (per-wave, no barrier needed)
    const int cm1 = cnt - 1;
    uint2 v0 = *(const uint2*)(hbase + osh[wv][0]);
    uint2 v1 = *(const uint2*)(hbase + osh[wv][1 > cm1 ? cm1 : 1]);
    uint2 v2 = *(const uint2*)(hbase + osh[wv][2 > cm1 ? cm1 : 2]);
    uint2 v3 = *(const uint2*)(hbase + osh[wv][3 > cm1 ? cm1 : 3]);
    for (int i = 0; i < cnt; ++i) {
      const float w = wsh[wv][i * 4 + hqi];
      const float hqv = qsh[wv][i * 4 + hqi];
      uint2 cur = v0; v0 = v1; v1 = v2; v2 = v3;
      int ni = i + 4; ni = ni > cm1 ? cm1 : ni;
      v3 = *(const uint2*)(hbase + osh[wv][ni]);
      den += w; sq += w * hqv;
      ax += w * __uint_as_float(cur.x << 16);
      ay += w * __uint_as_float(cur.x & 0xffff0000u);
      az += w * __uint_as_float(cur.y << 16);
      aw += w * __uint_as_float(cur.y & 0xffff0000u);
    }
  }
  const float4 bg = *(const float4*)(b_gat + lane * 4);
  ushort4 ov;
  ov.x = f2bf(ax / den + bg.x); ov.y = f2bf(ay / den + bg.y);
  ov.z = f2bf(az / den + bg.z); ov.w = f2bf(aw / den + bg.w);
  *(ushort4*)(outg + (size_t)n * 256 + lane * 4) = ov;
  float sd = sq / den;                              // per-head (uniform within head)
  float s0v = __shfl(sd, 0), s1v = __shfl(sd, 16);
  float s2v = __shfl(sd, 32), s3v = __shfl(sd, 48);
  if (lane == 0)
    score[n] = tanhf((s0v + s1v + s2v + s3v + cbuf[0]) * cbuf[1]);
}

// ---------------- top-k rank selection, 8 slices/graph (256 blocks) + x1 init ----------------
__global__ __launch_bounds__(1024) void topk_kernel(const float* __restrict__ score,
                                                    int* __restrict__ pidx_g,
                                                    float* __restrict__ tvs_g,
                                                    int* __restrict__ nmap,
                                                    float* __restrict__ out_batch,
                                                    float* __restrict__ out_x1) {
  __shared__ float scv[NPG];
  const int blk = blockIdx.x;                       // 256 = 32 graphs x 8 slices
  const int b = blk >> 3, slice = blk & 7;
  const int t = threadIdx.x;
  if (slice == 0 && t < 128)                        // init x1 for final's atomics
    out_x1[b * 128 + t] = (t < 64) ? 0.f : -INFINITY;
  scv[t] = score[b * NPG + t];
  __syncthreads();
  const int node = slice * 128 + (t >> 3);          // node within graph
  const int sub = t & 7;
  const float sc = scv[node];
  int rank = 0;
#pragma unroll
  for (int m = 0; m < 32; ++m) {
    const int j = (m * 8 + sub) * 4;
    const float4 s4 = *(const float4*)(&scv[j]);
    rank += (s4.x > sc) || (s4.x == sc && (j + 0) < node);
    rank += (s4.y > sc) || (s4.y == sc && (j + 1) < node);
    rank += (s4.z > sc) || (s4.z == sc && (j + 2) < node);
    rank += (s4.w > sc) || (s4.w == sc && (j + 3) < node);
  }
  rank += __shfl_xor(rank, 1, 64);                  // sum over sub (lane bits 0-2)
  rank += __shfl_xor(rank, 2, 64);
  rank += __shfl_xor(rank, 4, 64);
  if (sub == 0) {
    const int gn = b * NPG + node;
    if (rank < KK) {
      pidx_g[b * KK + rank] = node;
      tvs_g[b * KK + rank] = sc;
      nmap[gn] = b * KK + rank;
      out_batch[b * KK + rank] = (float)b;
    } else {
      nmap[gn] = -1;
    }
  }
}

// ---------------- final: gemm2xp + pool-atomics (blocks 0-255) | edge remap (256-2303) ----------------
__global__ __launch_bounds__(256) void final_kernel(const unsigned short* __restrict__ outg,
                                                    const unsigned short* __restrict__ Wlt,
                                                    const float* __restrict__ bl,
                                                    const int* __restrict__ pidx_g,
                                                    const float* __restrict__ tvs_g,
                                                    const int* __restrict__ ei,
                                                    const float* __restrict__ edge,
                                                    const int* __restrict__ nmap,
                                                    float* __restrict__ out_xp,
                                                    float* __restrict__ out_ei,
                                                    float* __restrict__ out_edge,
                                                    float* __restrict__ out_x1) {
  __shared__ float tile[64][68];
  __shared__ float pr[4][64];
  __shared__ float pmx[4][64];
  const int t = threadIdx.x;
  if (blockIdx.x >= 256) {                          // ---- edge remap / filter ----
    int e = (blockIdx.x - 256) * 256 + t;
    int s = ei[e], d = ei[EE + e];
    int ns = nmap[s], nd = nmap[d];
    bool valid = (ns >= 0) && (nd >= 0);
    out_ei[e] = (float)(valid ? ns : -1);
    out_ei[EE + e] = (float)(valid ? nd : -1);
    const float4* ef = (const float4*)(edge + (size_t)e * 8);
    float4 z = make_float4(0.f, 0.f, 0.f, 0.f);
    float4 v0 = valid ? ef[0] : z;
    float4 v1 = valid ? ef[1] : z;
    float4* eo = (float4*)(out_edge + (size_t)e * 8);
    eo[0] = v0; eo[1] = v1;
    return;
  }
  // ---- gemm2xp + pool partials ----
  const int lane = t & 63, wv = t >> 6;
  const int q = lane >> 4, nh = lane & 15;
  const int g = blockIdx.x >> 3, o = blockIdx.x & 7;
  const int r = o * 64 + wv * 16 + nh;              // kept-row rank within graph
  const int row = wv * 16 + nh;
  const int gnode = g * NPG + pidx_g[g * KK + r];
  const float tv = tvs_g[g * KK + r];
  f32x4 acc[4];
#pragma unroll
  for (int mt = 0; mt < 4; ++mt) acc[mt] = (f32x4){0.f, 0.f, 0.f, 0.f};
  const unsigned short* ar = outg + (size_t)gnode * 256;
#pragma unroll
  for (int kc = 0; kc < 8; ++kc) {
    short8 bf = *(const short8*)(ar + kc * 32 + q * 8);
#pragma unroll
    for (int mt = 0; mt < 4; ++mt) {
      short8 a = *(const short8*)(Wlt + (size_t)(mt * 16 + nh) * 256 + kc * 32 + q * 8);
      acc[mt] = __builtin_amdgcn_mfma_f32_16x16x32_bf16(a, bf, acc[mt], 0, 0, 0);
    }
  }
#pragma unroll
  for (int mt = 0; mt < 4; ++mt) {
    const int c4 = mt * 16 + q * 4;
    float4 bl4 = *(const float4*)(bl + c4);
    float4 o4 = make_float4((acc[mt][0] + bl4.x) * tv, (acc[mt][1] + bl4.y) * tv,
                            (acc[mt][2] + bl4.z) * tv, (acc[mt][3] + bl4.w) * tv);
    *(float4*)(out_xp + (size_t)(g * KK + r) * HID + c4) = o4;
    *(float4*)(&tile[row][c4]) = o4;
  }
  __syncthreads();
  {                                                 // partial sum/max over 64 rows
    const int ch = t & 63, qr = t >> 6;
    float s = 0.f, m = -INFINITY;
#pragma unroll
    for (int rr = 0; rr < 16; ++rr) {
      float v = tile[qr * 16 + rr][ch];
      s += v; m = fmaxf(m, v);
    }
    pr[qr][ch] = s; pmx[qr][ch] = m;
  }
  __syncthreads();
  if (t < 64) {
    float s = pr[0][t] + pr[1][t] + pr[2][t] + pr[3][t];
    float m = fmaxf(fmaxf(pmx[0][t], pmx[1][t]), fmaxf(pmx[2][t], pmx[3][t]));
    atomicAdd(&out_x1[g * 128 + t], s * (1.0f / KK));
    atomicMaxF(&out_x1[g * 128 + 64 + t], m);
  }
}

extern "C" void kernel_launch(void* const* d_in, const int* in_sizes, int n_in,
                              void* d_out, int out_size, void* d_ws, size_t ws_size,
                              hipStream_t stream) {
  const float* x      = (const float*)d_in[0];
  const int*   ei     = (const int*)d_in[1];
  const float* edge   = (const float*)d_in[2];
  const float* W      = (const float*)d_in[4];
  const float* a_src  = (const float*)d_in[5];
  const float* a_dst  = (const float*)d_in[6];
  const float* b_gat  = (const float*)d_in[7];
  const float* W_lin  = (const float*)d_in[8];
  const float* b_lin  = (const float*)d_in[9];
  const float* p_pool = (const float*)d_in[10];

  char* ws = (char*)d_ws;
  size_t off = 0;
  auto alloc = [&](size_t bytes) -> void* {
    void* p = ws + off;
    off += (bytes + 255) & ~(size_t)255;
    return p;
  };
  unsigned short* hbf  = (unsigned short*)alloc((size_t)NN * CC * 2);
  unsigned short* outg = (unsigned short*)alloc((size_t)NN * CC * 2);
  float* al_s    = (float*)alloc((size_t)NN * NH * 4);
  float* al_d    = (float*)alloc((size_t)NN * NH * 4);
  float* hq      = (float*)alloc((size_t)NN * NH * 4);
  float* score   = (float*)alloc((size_t)NN * 4);
  int*   row_ptr = (int*)alloc((size_t)(NN + 1) * 4);
  int*   col     = (int*)alloc((size_t)ETOT * 4);
  int*   nmap    = (int*)alloc((size_t)NN * 4);
  int*   pidx_g  = (int*)alloc((size_t)BB * KK * 4);
  float* tvs_g   = (float*)alloc((size_t)BB * KK * 4);
  unsigned short* Wt  = (unsigned short*)alloc((size_t)CC * INC * 2);
  unsigned short* Wlt = (unsigned short*)alloc((size_t)HID * CC * 2);
  float* Mg      = (float*)alloc((size_t)INC * 12 * 4);
  float* cbuf    = (float*)alloc(2 * 4);

  float* out_xp    = (float*)d_out;
  float* out_ei    = out_xp + (size_t)BB * KK * HID;
  float* out_edge  = out_ei + 2 * (size_t)EE;
  float* out_batch = out_edge + (size_t)EE * 8;
  float* out_x1    = out_batch + (size_t)BB * KK;

  prep_kernel<<<97, 1024, 0, stream>>>(W, a_src, a_dst, b_gat, W_lin, b_lin,
                                       p_pool, Mg, cbuf, Wt, Wlt, ei, row_ptr, col);
  stage2_kernel<<<1024, 256, 0, stream>>>(x, Mg, Wt, al_s, al_d, hq, hbf);
  agg_kernel<<<NN / 4, 256, 0, stream>>>(hbf, al_s, al_d, hq, row_ptr, col,
                                         b_gat, cbuf, outg, score);
  topk_kernel<<<256, 1024, 0, stream>>>(score, pidx_g, tvs_g, nmap, out_batch,
                                        out_x1);
  final_kernel<<<2304, 256, 0, stream>>>(outg, Wlt, b_lin, pidx_g, tvs_g,
                                         ei, edge, nmap, out_xp, out_ei,
                                         out_edge, out_x1);
}